// Round 26
// baseline (55.142 us; speedup 1.0000x reference)
//
#include <hip/hip_runtime.h>

#define DMODEL 1024
#define DHEAD 128
#define CHUNK 128
#define NCHUNK 32

typedef __attribute__((ext_vector_type(4))) float f32x4;
typedef __attribute__((ext_vector_type(8))) short bf16x8;

__device__ __forceinline__ unsigned short f2bf(float f) {
  union { float f; unsigned u; } v; v.f = f;
  unsigned r = v.u + 0x7FFF + ((v.u >> 16) & 1);   // RNE
  return (unsigned short)(r >> 16);
}
__device__ __forceinline__ float bf2f(unsigned short h) {
  union { unsigned u; float f; } v; v.u = ((unsigned)h) << 16;
  return v.f;
}
__device__ __forceinline__ unsigned cvtpk(float lo, float hi) {
  unsigned r;
  asm("v_cvt_pk_bf16_f32 %0, %1, %2" : "=v"(r) : "v"(lo), "v"(hi));
  return r;
}
__device__ __forceinline__ void gload16(const void* g, void* l) {
  __builtin_amdgcn_global_load_lds(
      (const __attribute__((address_space(1))) unsigned int*)g,
      (__attribute__((address_space(3))) unsigned int*)l, 16, 0, 0);
}

// ---------------- K0: W -> W^T bf16 via LDS tile transpose ----------------
__global__ __launch_bounds__(256) void transpose_w_kernel(
    const float* __restrict__ Wq, const float* __restrict__ Wk,
    const float* __restrict__ Wv, unsigned short* __restrict__ WT) {
  __shared__ float ts[64][65];
  const int w = blockIdx.y;
  const int kb = blockIdx.x >> 1;
  const int nb = blockIdx.x & 1;
  const float* W = (w == 0) ? Wq : (w == 1) ? Wk : Wv;
  const int tid = threadIdx.x;
  const int rr = tid >> 4, cc = tid & 15;

#pragma unroll
  for (int i = 0; i < 4; ++i) {
    int r = i * 16 + rr;
    float4 v = *reinterpret_cast<const float4*>(
        &W[(size_t)(kb * 64 + r) * DHEAD + nb * 64 + cc * 4]);
    ts[r][cc * 4 + 0] = v.x;
    ts[r][cc * 4 + 1] = v.y;
    ts[r][cc * 4 + 2] = v.z;
    ts[r][cc * 4 + 3] = v.w;
  }
  __syncthreads();
#pragma unroll
  for (int i = 0; i < 4; ++i) {
    int nr = i * 16 + rr;
    ushort4 u;
    u.x = f2bf(ts[cc * 4 + 0][nr]);
    u.y = f2bf(ts[cc * 4 + 1][nr]);
    u.z = f2bf(ts[cc * 4 + 2][nr]);
    u.w = f2bf(ts[cc * 4 + 3][nr]);
    *reinterpret_cast<ushort4*>(
        &WT[(size_t)w * (DHEAD * DMODEL) + (size_t)(nb * 64 + nr) * DMODEL +
            kb * 64 + cc * 4]) = u;
  }
}

// ---------------- K1: FUSED projection + phi, 2-deep prefetch ------
__global__ __launch_bounds__(256) void proj_kernel(
    const float* __restrict__ x, const unsigned short* __restrict__ WT,
    unsigned short* __restrict__ phiQ, unsigned short* __restrict__ phiK,
    unsigned short* __restrict__ Vb) {
  const int bid = blockIdx.x;
  const int nh = (bid >> 3) & 1;
  const int mt = (bid & 7) + ((bid >> 4) << 3);   // 0..255
  const int n0 = nh << 6;
  const int m0 = mt << 6;

  __shared__ unsigned short wl[2][3][64][64];   // 48 KB, swizzled

  const int tid = threadIdx.x;
  const int wave = tid >> 6;
  const int lane = tid & 63;
  const int lrow = lane & 15, kgrp = lane >> 4;

  const float* xrow = &x[(size_t)(m0 + wave * 16 + lrow) * DMODEL + kgrp * 8];

  f32x4 acc[3][4];
#pragma unroll
  for (int w3 = 0; w3 < 3; ++w3)
#pragma unroll
    for (int nt = 0; nt < 4; ++nt) acc[w3][nt] = (f32x4)0.0f;

  float4 va[4], vb[4];

#define WSTAGE(T, B)                                                        \
  {                                                                         \
    _Pragma("unroll")                                                       \
    for (int i = 0; i < 6; ++i) {                                           \
      int instr = i * 4 + wave;                                             \
      int w3 = instr >> 3;                                                  \
      int jj = instr & 7;                                                   \
      int row = jj * 8 + (lane >> 3);                                       \
      int slot = lane & 7;                                                  \
      int gcol = (slot ^ (row & 7)) << 3;                                   \
      gload16(&WT[(size_t)w3 * (DHEAD * DMODEL) +                           \
                  (size_t)(n0 + row) * DMODEL + (T) * 64 + gcol],           \
              (char*)wl + (B) * 24576 + instr * 1024);                      \
    }                                                                       \
  }
#define XLOAD(T, V)                                                         \
  {                                                                         \
    _Pragma("unroll")                                                       \
    for (int ks = 0; ks < 2; ++ks) {                                        \
      V[2 * ks]     = *reinterpret_cast<const float4*>(xrow + (T) * 64 + ks * 32);     \
      V[2 * ks + 1] = *reinterpret_cast<const float4*>(xrow + (T) * 64 + ks * 32 + 4); \
    }                                                                       \
  }
#define COMPUTE(V, B)                                                       \
  {                                                                         \
    __builtin_amdgcn_s_setprio(1);                                          \
    _Pragma("unroll")                                                       \
    for (int ks2 = 0; ks2 < 2; ++ks2) {                                     \
      union { unsigned u[4]; bf16x8 v; } p;                                 \
      p.u[0] = cvtpk(V[2 * ks2].x, V[2 * ks2].y);                           \
      p.u[1] = cvtpk(V[2 * ks2].z, V[2 * ks2].w);                           \
      p.u[2] = cvtpk(V[2 * ks2 + 1].x, V[2 * ks2 + 1].y);                   \
      p.u[3] = cvtpk(V[2 * ks2 + 1].z, V[2 * ks2 + 1].w);                   \
      bf16x8 af = p.v;                                                      \
      _Pragma("unroll")                                                     \
      for (int w3 = 0; w3 < 3; ++w3)                                        \
        _Pragma("unroll")                                                   \
        for (int nt = 0; nt < 4; ++nt) {                                    \
          int brow = nt * 16 + lrow;                                        \
          int sl = (ks2 * 4 + kgrp) ^ (brow & 7);                           \
          bf16x8 bf = *reinterpret_cast<const bf16x8*>(                     \
              (char*)wl + (B) * 24576 + w3 * 8192 + brow * 128 + sl * 16);  \
          acc[w3][nt] = __builtin_amdgcn_mfma_f32_16x16x32_bf16(            \
              af, bf, acc[w3][nt], 0, 0, 0);                                \
        }                                                                   \
    }                                                                       \
    __builtin_amdgcn_s_setprio(0);                                          \
  }

  WSTAGE(0, 0);
  XLOAD(0, va);
  __syncthreads();

#pragma unroll
  for (int tt = 0; tt < 8; ++tt) {
    const int t = tt * 2;
    if (t + 1 < 16) { WSTAGE(t + 1, 1); XLOAD(t + 1, vb); }
    COMPUTE(va, 0);
    __syncthreads();
    if (t + 2 < 16) { WSTAGE(t + 2, 0); XLOAD(t + 2, va); }
    COMPUTE(vb, 1);
    __syncthreads();
  }
#undef WSTAGE
#undef XLOAD
#undef COMPUTE

#pragma unroll
  for (int w3 = 0; w3 < 3; ++w3) {
    unsigned short* outp = (w3 == 0) ? phiQ : (w3 == 1) ? phiK : Vb;
#pragma unroll
    for (int nt = 0; nt < 4; ++nt)
#pragma unroll
      for (int r = 0; r < 4; ++r) {
        int row = m0 + wave * 16 + kgrp * 4 + r;
        int col = n0 + nt * 16 + lrow;
        float v = acc[w3][nt][r];
        if (w3 < 2) v = (v > 0.0f) ? (v + 1.0f) : __expf(v);
        outp[(size_t)row * DHEAD + col] = f2bf(v);
      }
  }
}

// ---------------- K2: per-chunk KV^T = v^T @ k (dv-split), ks colsums ----------------
__global__ __launch_bounds__(256) void chunkkv_kernel(
    const unsigned short* __restrict__ phiK, const unsigned short* __restrict__ Vb,
    float* __restrict__ KVc, float* __restrict__ ksc) {
  const int c = blockIdx.x;
  const int yv = blockIdx.y;
  const size_t base = (size_t)c * CHUNK * DHEAD;
  __shared__ unsigned short kt[128][136];
  __shared__ unsigned short vt[64][136];
  __shared__ float csum[2][128];
  const int tid = threadIdx.x;
  const int wave = tid >> 6, lane = tid & 63;
  const int lrow = lane & 15, kgrp = lane >> 4;

  {
    int t = tid & 127, dp = tid >> 7;
#pragma unroll
    for (int i = 0; i < 8; ++i) {
      int d0 = (dp + 2 * i) * 8;
      uint4 k4 = *reinterpret_cast<const uint4*>(&phiK[base + (size_t)t * DHEAD + d0]);
      const unsigned short* kp = reinterpret_cast<const unsigned short*>(&k4);
#pragma unroll
      for (int j = 0; j < 8; ++j) kt[d0 + j][t] = kp[j];
    }
#pragma unroll
    for (int i = 0; i < 4; ++i) {
      int dl = (dp + 2 * i) * 8;
      uint4 v4 = *reinterpret_cast<const uint4*>(
          &Vb[base + (size_t)t * DHEAD + yv * 64 + dl]);
      const unsigned short* vp = reinterpret_cast<const unsigned short*>(&v4);
#pragma unroll
      for (int j = 0; j < 8; ++j) vt[dl + j][t] = vp[j];
    }
  }
  __syncthreads();

  f32x4 acc[8];
#pragma unroll
  for (int j = 0; j < 8; ++j) acc[j] = (f32x4)0.0f;
#pragma unroll
  for (int ks = 0; ks < 4; ++ks) {
    int t0 = ks * 32 + kgrp * 8;
    bf16x8 afrag = *reinterpret_cast<const bf16x8*>(&vt[wave * 16 + lrow][t0]);
#pragma unroll
    for (int tc = 0; tc < 8; ++tc) {
      bf16x8 bfrag = *reinterpret_cast<const bf16x8*>(&kt[tc * 16 + lrow][t0]);
      acc[tc] = __builtin_amdgcn_mfma_f32_16x16x32_bf16(afrag, bfrag, acc[tc], 0, 0, 0);
    }
  }
  float* KVout = KVc + (size_t)c * (DHEAD * DHEAD);
#pragma unroll
  for (int tc = 0; tc < 8; ++tc)
#pragma unroll
    for (int r = 0; r < 4; ++r) {
      int dv = yv * 64 + wave * 16 + kgrp * 4 + r;
      int d = tc * 16 + lrow;
      KVout[dv * DHEAD + d] = acc[tc][r];
    }
  if (yv == 0) {
    int d = tid & 127, hh = tid >> 7;
    float s = 0.0f;
    for (int t = hh * 64; t < hh * 64 + 64; ++t) s += bf2f(kt[d][t]);
    csum[hh][d] = s;
    __syncthreads();
    if (tid < 128) ksc[(size_t)c * DHEAD + tid] = csum[0][tid] + csum[1][tid];
  }
}

// ---------------- K3: exclusive prefix over chunks ----------------
__global__ __launch_bounds__(256) void prefix_kernel(
    const float* __restrict__ KVc, const float* __restrict__ ksc,
    unsigned short* __restrict__ KVp, float* __restrict__ ksp) {
  if (blockIdx.x < 256) {
    int id = blockIdx.x * 256 + threadIdx.x;
    int b = id >> 14;
    int e = id & 16383;
    size_t base = (size_t)b * NCHUNK * 16384 + e;
    float acc = 0.0f;
    for (int c = 0; c < NCHUNK; ++c) {
      KVp[base + (size_t)c * 16384] = f2bf(acc);
      acc += KVc[base + (size_t)c * 16384];
    }
  } else {
    for (int i = threadIdx.x; i < 512; i += 256) {
      int b = i >> 7, d = i & 127;
      size_t base = (size_t)b * NCHUNK * DHEAD + d;
      float acc = 0.0f;
      for (int c = 0; c < NCHUNK; ++c) {
        ksp[base + (size_t)c * DHEAD] = acc;
        acc += ksc[base + (size_t)c * DHEAD];
      }
    }
  }
}

// ---------------- K4: per-chunk output, vbuf time-shared (~71 KB -> 2 blk/CU) ----
// vbuf used as [128 dv][64 t (+4 pad)] for PV t-halves, then reinterpreted as
// [64 dv][136 d] for the two q@KV dv-halves (8704 shorts, exact fit).
__global__ __launch_bounds__(256) void out_kernel(
    const unsigned short* __restrict__ phiQ, const unsigned short* __restrict__ phiK,
    const unsigned short* __restrict__ Vb, const unsigned short* __restrict__ KVp,
    const float* __restrict__ ksp, float* __restrict__ outp) {
  const int c = blockIdx.x;
  const int h = blockIdx.y;
  const size_t kvbase = (size_t)c * CHUNK * DHEAD;
  const size_t qbase = kvbase + (size_t)h * 64 * DHEAD;
  __shared__ unsigned short qb[64][136];
  __shared__ unsigned short kb[128][136];
  __shared__ unsigned short vbuf[128][68];   // 17.4 KB dual-shape pool
  __shared__ float dsum[4][64];
  __shared__ float ks_l[128];
  const int tid = threadIdx.x;
  const int wave = tid >> 6, lane = tid & 63;
  const int lrow = lane & 15, kgrp = lane >> 4;
  unsigned short (*kvb)[136] = reinterpret_cast<unsigned short(*)[136]>(&vbuf[0][0]);

#pragma unroll
  for (int it = 0; it < 4; ++it) {
    int idx = it * 256 + tid;
    int t = idx >> 4;
    int d0 = (idx & 15) << 3;
    *reinterpret_cast<uint4*>(&qb[t][d0]) =
        *reinterpret_cast<const uint4*>(&phiQ[qbase + (size_t)t * DHEAD + d0]);
  }
  if (tid < 128) ks_l[tid] = ksp[(size_t)c * DHEAD + tid];
  {
    const int nit = (h == 0) ? 4 : 8;
    for (int it = 0; it < nit; ++it) {
      int idx = it * 256 + tid;
      int t = idx >> 4;
      int d0 = (idx & 15) << 3;
      *reinterpret_cast<uint4*>(&kb[t][d0]) =
          *reinterpret_cast<const uint4*>(&phiK[kvbase + (size_t)t * DHEAD + d0]);
    }
  }
  // vbuf phase 1: v^T (all 128 dv) for t = 0..63
  {
    int t = tid & 63, dp = tid >> 6;
#pragma unroll
    for (int i = 0; i < 4; ++i) {
      int d0 = (dp + 4 * i) * 8;             // 0..120
      uint4 v4 = *reinterpret_cast<const uint4*>(&Vb[kvbase + (size_t)t * DHEAD + d0]);
      const unsigned short* vp = reinterpret_cast<const unsigned short*>(&v4);
#pragma unroll
      for (int j = 0; j < 8; ++j) vbuf[d0 + j][t] = vp[j];
    }
  }
  __syncthreads();

  // ---- S = q @ k^T, mask, P -> kb rows 0..63 ----
  if (h == 0) {
    f32x4 sa[4];
#pragma unroll
    for (int i = 0; i < 4; ++i) sa[i] = (f32x4)0.0f;
#pragma unroll
    for (int ks = 0; ks < 4; ++ks) {
      int d0 = ks * 32 + kgrp * 8;
      bf16x8 af = *reinterpret_cast<const bf16x8*>(&qb[wave * 16 + lrow][d0]);
#pragma unroll
      for (int tc = 0; tc < 4; ++tc) {
        bf16x8 bf = *reinterpret_cast<const bf16x8*>(&kb[tc * 16 + lrow][d0]);
        sa[tc] = __builtin_amdgcn_mfma_f32_16x16x32_bf16(af, bf, sa[tc], 0, 0, 0);
      }
    }
    __syncthreads();
#pragma unroll
    for (int tc = 0; tc < 4; ++tc)
#pragma unroll
      for (int r = 0; r < 4; ++r) {
        int trow = wave * 16 + kgrp * 4 + r;
        int s = tc * 16 + lrow;
        kb[trow][s] = f2bf((s <= trow) ? sa[tc][r] : 0.0f);
      }
  } else {
    f32x4 sa[8];
#pragma unroll
    for (int i = 0; i < 8; ++i) sa[i] = (f32x4)0.0f;
#pragma unroll
    for (int ks = 0; ks < 4; ++ks) {
      int d0 = ks * 32 + kgrp * 8;
      bf16x8 af = *reinterpret_cast<const bf16x8*>(&qb[wave * 16 + lrow][d0]);
#pragma unroll
      for (int tc = 0; tc < 8; ++tc) {
        bf16x8 bf = *reinterpret_cast<const bf16x8*>(&kb[tc * 16 + lrow][d0]);
        sa[tc] = __builtin_amdgcn_mfma_f32_16x16x32_bf16(af, bf, sa[tc], 0, 0, 0);
      }
    }
    __syncthreads();
#pragma unroll
    for (int tc = 0; tc < 8; ++tc)
#pragma unroll
      for (int r = 0; r < 4; ++r) {
        int trow = wave * 16 + kgrp * 4 + r;
        int s = tc * 16 + lrow;
        kb[trow][s] = f2bf((s <= 64 + trow) ? sa[tc][r] : 0.0f);
      }
  }
  __syncthreads();   // P visible

  // ---- den = rowsum(P) + q . ks_prefix ----
  {
    int t = tid & 63, h4 = tid >> 6;
    float s = 0.0f;
    if (h4 < 2) {
      if (h4 == 0 || h == 1) {
        for (int j = h4 * 64; j < h4 * 64 + 64; ++j) s += bf2f(kb[t][j]);
      }
    } else {
      for (int j = (h4 - 2) * 64; j < (h4 - 2) * 64 + 64; ++j)
        s += bf2f(qb[t][j]) * ks_l[j];
    }
    dsum[h4][t] = s;
  }

  // ---- O = P @ v, pass 1 (t = 0..63; B rows = all 128 dv) ----
  f32x4 acc[8];
#pragma unroll
  for (int i = 0; i < 8; ++i) acc[i] = (f32x4)0.0f;
#pragma unroll
  for (int ks = 0; ks < 2; ++ks) {
    int t0 = ks * 32 + kgrp * 8;
    bf16x8 af = *reinterpret_cast<const bf16x8*>(&kb[wave * 16 + lrow][t0]);
#pragma unroll
    for (int tc = 0; tc < 8; ++tc) {
      bf16x8 bf = *reinterpret_cast<const bf16x8*>(&vbuf[tc * 16 + lrow][t0]);
      acc[tc] = __builtin_amdgcn_mfma_f32_16x16x32_bf16(af, bf, acc[tc], 0, 0, 0);
    }
  }
  if (h == 1) {
    __syncthreads();   // done reading vbuf (t-half 1)
    // vbuf phase 2: v^T for t = 64..127
    {
      int t = tid & 63, dp = tid >> 6;
#pragma unroll
      for (int i = 0; i < 4; ++i) {
        int d0 = (dp + 4 * i) * 8;
        uint4 v4 = *reinterpret_cast<const uint4*>(
            &Vb[kvbase + (size_t)(64 + t) * DHEAD + d0]);
        const unsigned short* vp = reinterpret_cast<const unsigned short*>(&v4);
#pragma unroll
        for (int j = 0; j < 8; ++j) vbuf[d0 + j][t] = vp[j];
      }
    }
    __syncthreads();
    // ---- O = P @ v, pass 2 (t = 64..127) ----
#pragma unroll
    for (int ks = 2; ks < 4; ++ks) {
      int t0 = ks * 32 + kgrp * 8;
      bf16x8 af = *reinterpret_cast<const bf16x8*>(&kb[wave * 16 + lrow][t0]);
#pragma unroll
      for (int tc = 0; tc < 8; ++tc) {
        bf16x8 bf = *reinterpret_cast<const bf16x8*>(&vbuf[tc * 16 + lrow][t0 - 64]);
        acc[tc] = __builtin_amdgcn_mfma_f32_16x16x32_bf16(af, bf, acc[tc], 0, 0, 0);
      }
    }
  }
  __syncthreads();   // done reading vbuf as v^T

  // ---- kvb phase 3: KV prefix rows dv = 0..63 ----
#pragma unroll
  for (int it = 0; it < 4; ++it) {
    int idx = it * 256 + tid;
    int dv = idx >> 4;                       // 0..63
    int d0 = (idx & 15) << 3;
    *reinterpret_cast<uint4*>(&kvb[dv][d0]) =
        *reinterpret_cast<const uint4*>(&KVp[(size_t)c * 16384 + (size_t)dv * DHEAD + d0]);
  }
  __syncthreads();
  // ---- O += q @ KV, half 1 (output cols 0..63) ----
#pragma unroll
  for (int ks = 0; ks < 4; ++ks) {
    int d0 = ks * 32 + kgrp * 8;
    bf16x8 af = *reinterpret_cast<const bf16x8*>(&qb[wave * 16 + lrow][d0]);
#pragma unroll
    for (int tc = 0; tc < 4; ++tc) {
      bf16x8 bf = *reinterpret_cast<const bf16x8*>(&kvb[tc * 16 + lrow][d0]);
      acc[tc] = __builtin_amdgcn_mfma_f32_16x16x32_bf16(af, bf, acc[tc], 0, 0, 0);
    }
  }
  __syncthreads();   // done reading kvb half 1

  // ---- kvb phase 4: KV prefix rows dv = 64..127 ----
#pragma unroll
  for (int it = 0; it < 4; ++it) {
    int idx = it * 256 + tid;
    int dv = idx >> 4;
    int d0 = (idx & 15) << 3;
    *reinterpret_cast<uint4*>(&kvb[dv][d0]) =
        *reinterpret_cast<const uint4*>(
            &KVp[(size_t)c * 16384 + (size_t)(64 + dv) * DHEAD + d0]);
  }
  __syncthreads();
  // ---- O += q @ KV, half 2 (output cols 64..127) ----
#pragma unroll
  for (int ks = 0; ks < 4; ++ks) {
    int d0 = ks * 32 + kgrp * 8;
    bf16x8 af = *reinterpret_cast<const bf16x8*>(&qb[wave * 16 + lrow][d0]);
#pragma unroll
    for (int tc = 0; tc < 4; ++tc) {
      bf16x8 bf = *reinterpret_cast<const bf16x8*>(&kvb[tc * 16 + lrow][d0]);
      acc[4 + tc] = __builtin_amdgcn_mfma_f32_16x16x32_bf16(af, bf, acc[4 + tc], 0, 0, 0);
    }
  }

  // ---- divide + store ----
#pragma unroll
  for (int tc = 0; tc < 8; ++tc)
#pragma unroll
    for (int r = 0; r < 4; ++r) {
      int trow = wave * 16 + kgrp * 4 + r;
      int dv = tc * 16 + lrow;
      float den = dsum[0][trow] + dsum[1][trow] + dsum[2][trow] + dsum[3][trow];
      outp[qbase + (size_t)trow * DHEAD + dv] = acc[tc][r] / den;
    }
}

extern "C" void kernel_launch(void* const* d_in, const int* in_sizes, int n_in,
                              void* d_out, int out_size, void* d_ws, size_t ws_size,
                              hipStream_t stream) {
  const float* x  = (const float*)d_in[0];
  const float* Wq = (const float*)d_in[1];
  const float* Wk = (const float*)d_in[2];
  const float* Wv = (const float*)d_in[3];
  float* out = (float*)d_out;
  char* ws = (char*)d_ws;
  unsigned short* phiQ = (unsigned short*)(ws + 0);          // 4 MB
  unsigned short* phiK = (unsigned short*)(ws + 4194304);    // 4 MB
  unsigned short* Vb   = (unsigned short*)(ws + 8388608);    // 4 MB
  unsigned short* WT   = (unsigned short*)(ws + 12582912);   // 768 KB
  float*          KVc  = (float*)(ws + 13369344);            // 8 MB
  unsigned short* KVp  = (unsigned short*)(ws + 21757952);   // 4 MB
  float*          ksc  = (float*)(ws + 25952256);            // 64 KB
  float*          ksp  = (float*)(ws + 26017792);            // 64 KB

  transpose_w_kernel<<<dim3(32, 3), 256, 0, stream>>>(Wq, Wk, Wv, WT);
  proj_kernel<<<512, 256, 0, stream>>>(x, WT, phiQ, phiK, Vb);
  chunkkv_kernel<<<dim3(128, 2), 256, 0, stream>>>(phiK, Vb, KVc, ksc);
  prefix_kernel<<<257, 256, 0, stream>>>(KVc, ksc, KVp, ksp);
  out_kernel<<<dim3(128, 2), 256, 0, stream>>>(phiQ, phiK, Vb, KVp, ksp, out);
}